// Round 5
// baseline (97.378 us; speedup 1.0000x reference)
//
#include <hip/hip_runtime.h>

// E2M1 (MXFP4-style) activation quantizer, block size 32, LAYER_MAX = 6.0.
// Outputs concatenated in d_out as float32:
//   [0, N)        x_deq
//   [N, 2N)       encoded (values 0..15, stored as float)
//   [2N, 2N+N/32) scale_uint8 (values 0..255, stored as float)
//
// Layout: each lane handles 8 consecutive floats (2x 16B vectors), so a
// 4-lane group covers one 32-element quant block. amax reduce = 2 shfl_xor.

typedef float f32x4 __attribute__((ext_vector_type(4)));

constexpr int TPB = 256;

struct EncOut { float dq, ef; };

__device__ __forceinline__ EncOut enc1(float xv, float rscale, float scale) {
    const float axn = fabsf(xv) * rscale;   // exact: power-of-2 scale
    const int ord = (axn > 0.25f) + (axn > 0.75f) + (axn > 1.25f) +
                    (axn > 1.75f) + (axn > 2.5f)  + (axn > 3.5f) +
                    (axn > 5.0f);
    // E2M1 table {0,0.5,1,1.5,2,3,4,6} without runtime-indexed array
    const float m = (ord <= 4) ? (float)ord * 0.5f
                     : (ord == 5 ? 3.0f : (ord == 6 ? 4.0f : 6.0f));
    const bool pos = xv > 0.0f;             // sign_bit = 1 for x <= 0
    EncOut o;
    o.ef = (float)(pos ? ord : ord + 8);
    o.dq = (pos ? m : -m) * scale;
    return o;
}

__global__ __launch_bounds__(TPB) void e2m1_quant_kernel(
    const float* __restrict__ x,
    float* __restrict__ xdeq,
    float* __restrict__ enc,
    float* __restrict__ scl,
    int n8)
{
    const int tid    = blockIdx.x * TPB + threadIdx.x;
    const int stride = gridDim.x * TPB;

    for (int i = tid; i < n8; i += stride) {
        const f32x4* xp = reinterpret_cast<const f32x4*>(x) + 2 * (size_t)i;
        const f32x4 v0 = __builtin_nontemporal_load(xp);
        const f32x4 v1 = __builtin_nontemporal_load(xp + 1);

        // per-lane amax of 8 elems, then reduce across the 4-lane group
        float a = fmaxf(fmaxf(fmaxf(fabsf(v0.x), fabsf(v0.y)),
                              fmaxf(fabsf(v0.z), fabsf(v0.w))),
                        fmaxf(fmaxf(fabsf(v1.x), fabsf(v1.y)),
                              fmaxf(fabsf(v1.z), fabsf(v1.w))));
        a = fmaxf(a, __shfl_xor(a, 1, 4));
        a = fmaxf(a, __shfl_xor(a, 2, 4));

        // e8m0 = ceil(max(log2(a/6), -127)), exactly, branchless from bits:
        // for d > 2^-127:  e = biased_exp - 127 + (mantissa != 0)
        // for d <= 2^-127 (incl. 0 and subnormals): clamp to -127
        const float d = a / 6.0f;            // IEEE division (rounding matters)
        const unsigned ud = __float_as_uint(d);
        const int e8m0 = (ud <= 0x00400000u)
                           ? -127
                           : (int)(ud >> 23) - 127 + ((ud & 0x7fffffu) ? 1 : 0);

        // power-of-two scale -> all multiplies below are exact
        const float rscale = __uint_as_float(((unsigned)(127 - e8m0)) << 23); // 2^-e8m0
        const float scale  = (e8m0 <= -127)
                               ? __uint_as_float(0x00400000u)                 // 2^-127
                               : __uint_as_float(((unsigned)(e8m0 + 127)) << 23);

        f32x4 dq0, dq1, ef0, ef1;
        EncOut o;
        o = enc1(v0.x, rscale, scale); dq0.x = o.dq; ef0.x = o.ef;
        o = enc1(v0.y, rscale, scale); dq0.y = o.dq; ef0.y = o.ef;
        o = enc1(v0.z, rscale, scale); dq0.z = o.dq; ef0.z = o.ef;
        o = enc1(v0.w, rscale, scale); dq0.w = o.dq; ef0.w = o.ef;
        o = enc1(v1.x, rscale, scale); dq1.x = o.dq; ef1.x = o.ef;
        o = enc1(v1.y, rscale, scale); dq1.y = o.dq; ef1.y = o.ef;
        o = enc1(v1.z, rscale, scale); dq1.z = o.dq; ef1.z = o.ef;
        o = enc1(v1.w, rscale, scale); dq1.w = o.dq; ef1.w = o.ef;

        f32x4* dqp = reinterpret_cast<f32x4*>(xdeq) + 2 * (size_t)i;
        f32x4* efp = reinterpret_cast<f32x4*>(enc)  + 2 * (size_t)i;
        __builtin_nontemporal_store(dq0, dqp);
        __builtin_nontemporal_store(dq1, dqp + 1);
        __builtin_nontemporal_store(ef0, efp);
        __builtin_nontemporal_store(ef1, efp + 1);
        if ((i & 3) == 0)                    // first lane of each 4-lane group
            __builtin_nontemporal_store((float)(e8m0 + 127), scl + (i >> 2));
    }
}

extern "C" void kernel_launch(void* const* d_in, const int* in_sizes, int n_in,
                              void* d_out, int out_size, void* d_ws, size_t ws_size,
                              hipStream_t stream) {
    const float* x = (const float*)d_in[0];
    float* out = (float*)d_out;

    const int n  = in_sizes[0];        // 4096*8192
    const int n8 = n / 8;

    float* xdeq = out;
    float* enc  = out + (size_t)n;
    float* scl  = out + 2 * (size_t)n;

    int blocks = (n8 + TPB - 1) / TPB;
    if (blocks > 2048) blocks = 2048;  // grid-stride the rest (G11)

    e2m1_quant_kernel<<<blocks, TPB, 0, stream>>>(x, xdeq, enc, scl, n8);
}

// Round 6
// 70.856 us; speedup vs baseline: 1.3743x; 1.3743x over previous
//
#include <hip/hip_runtime.h>

// E2M1 (MXFP4-style) activation quantizer, block size 32, LAYER_MAX = 6.0.
// Outputs concatenated in d_out as float32:
//   [0, N)        x_deq
//   [N, 2N)       encoded (values 0..15, stored as float)
//   [2N, 2N+N/32) scale_uint8 (values 0..255, stored as float)
//
// Round-2 memory pattern (known 85.8us): 1x float4 per lane, fully
// line-dense coalesced loads; 8-lane group = one 32-elem quant block.
// Round-6 deltas vs round-2: branchless e8m0, nontemporal STORES only.

typedef float f32x4 __attribute__((ext_vector_type(4)));

constexpr int TPB = 256;

struct EncOut { float dq, ef; };

__device__ __forceinline__ EncOut enc1(float xv, float rscale, float scale) {
    const float axn = fabsf(xv) * rscale;   // exact: power-of-2 scale
    const int ord = (axn > 0.25f) + (axn > 0.75f) + (axn > 1.25f) +
                    (axn > 1.75f) + (axn > 2.5f)  + (axn > 3.5f) +
                    (axn > 5.0f);
    // E2M1 table {0,0.5,1,1.5,2,3,4,6} without runtime-indexed array
    const float m = (ord <= 4) ? (float)ord * 0.5f
                     : (ord == 5 ? 3.0f : (ord == 6 ? 4.0f : 6.0f));
    const bool pos = xv > 0.0f;             // sign_bit = 1 for x <= 0
    EncOut o;
    o.ef = (float)(pos ? ord : ord + 8);
    o.dq = (pos ? m : -m) * scale;
    return o;
}

__global__ __launch_bounds__(TPB) void e2m1_quant_kernel(
    const float* __restrict__ x,
    float* __restrict__ xdeq,
    float* __restrict__ enc,
    float* __restrict__ scl,
    int n4)
{
    const int tid    = blockIdx.x * TPB + threadIdx.x;
    const int stride = gridDim.x * TPB;

    for (int i = tid; i < n4; i += stride) {
        const f32x4 v = reinterpret_cast<const f32x4*>(x)[i];  // regular load

        // per-lane amax of 4 elems, then reduce across the 8-lane group
        // (8 lanes x 4 elems = one 32-element quant block)
        float a = fmaxf(fmaxf(fabsf(v.x), fabsf(v.y)),
                        fmaxf(fabsf(v.z), fabsf(v.w)));
        a = fmaxf(a, __shfl_xor(a, 1, 8));
        a = fmaxf(a, __shfl_xor(a, 2, 8));
        a = fmaxf(a, __shfl_xor(a, 4, 8));

        // e8m0 = ceil(max(log2(a/6), -127)), exactly, branchless from bits:
        // for d > 2^-127:  e = biased_exp - 127 + (mantissa != 0)
        // for d <= 2^-127 (incl. 0 and subnormals): clamp to -127
        const float d = a / 6.0f;            // IEEE division (rounding matters)
        const unsigned ud = __float_as_uint(d);
        const int e8m0 = (ud <= 0x00400000u)
                           ? -127
                           : (int)(ud >> 23) - 127 + ((ud & 0x7fffffu) ? 1 : 0);

        // power-of-two scale -> all multiplies below are exact
        const float rscale = __uint_as_float(((unsigned)(127 - e8m0)) << 23); // 2^-e8m0
        const float scale  = (e8m0 <= -127)
                               ? __uint_as_float(0x00400000u)                 // 2^-127
                               : __uint_as_float(((unsigned)(e8m0 + 127)) << 23);

        f32x4 dq, ef;
        EncOut o;
        o = enc1(v.x, rscale, scale); dq.x = o.dq; ef.x = o.ef;
        o = enc1(v.y, rscale, scale); dq.y = o.dq; ef.y = o.ef;
        o = enc1(v.z, rscale, scale); dq.z = o.dq; ef.z = o.ef;
        o = enc1(v.w, rscale, scale); dq.w = o.dq; ef.w = o.ef;

        __builtin_nontemporal_store(dq, reinterpret_cast<f32x4*>(xdeq) + i);
        __builtin_nontemporal_store(ef, reinterpret_cast<f32x4*>(enc) + i);
        if ((i & 7) == 0)                    // first lane of each 8-lane group
            __builtin_nontemporal_store((float)(e8m0 + 127), scl + (i >> 3));
    }
}

extern "C" void kernel_launch(void* const* d_in, const int* in_sizes, int n_in,
                              void* d_out, int out_size, void* d_ws, size_t ws_size,
                              hipStream_t stream) {
    const float* x = (const float*)d_in[0];
    float* out = (float*)d_out;

    const int n  = in_sizes[0];        // 4096*8192
    const int n4 = n / 4;

    float* xdeq = out;
    float* enc  = out + (size_t)n;
    float* scl  = out + 2 * (size_t)n;

    int blocks = (n4 + TPB - 1) / TPB;
    if (blocks > 2048) blocks = 2048;  // grid-stride the rest (G11)

    e2m1_quant_kernel<<<blocks, TPB, 0, stream>>>(x, xdeq, enc, scl, n4);
}